// Round 8
// baseline (8346.043 us; speedup 1.0000x reference)
//
#include <hip/hip_runtime.h>
#include <hip/hip_bf16.h>
#include <float.h>
#include <math.h>

#define NB 256
#define LTXT 77
#define DIM 768
#define DEPTH 12
#define HEADS 12
#define DH 64
#define NTOK 80
#define NKEY 81
#define NROWS (NB*NTOK)       // 20480
#define FFH 3072
#define FF2C 6144
#define INNER 768
#define SROW 100              // f32 per S row (mod-32 = 4 -> 2-way banks)

typedef __hip_bfloat16 bf16;
typedef __attribute__((ext_vector_type(8))) short short8;
typedef __attribute__((ext_vector_type(4))) float f32x4;
typedef __attribute__((ext_vector_type(16))) float f32x16;

#define BARRIER() asm volatile("s_barrier" ::: "memory")
#define WAITV(n)  asm volatile("s_waitcnt vmcnt(" #n ")" ::: "memory")

__device__ __forceinline__ unsigned short f2bf(float f) {
    __hip_bfloat16 h = __float2bfloat16(f);
    return __builtin_bit_cast(unsigned short, h);
}

// ---------------- token build ----------------
__global__ void build_tokens(const float* __restrict__ text_enc,
                             const float* __restrict__ text_emb,
                             const float* __restrict__ time_tab,
                             const float* __restrict__ lquery,
                             const int* __restrict__ tsteps,
                             float* __restrict__ x) {
    int idx = blockIdx.x * 256 + threadIdx.x;
    if (idx >= NROWS * DIM) return;
    int d = idx % DIM;
    int row = idx / DIM;
    int b = row / NTOK, p = row % NTOK;
    float v;
    if (p < LTXT)            v = text_enc[((size_t)b * LTXT + p) * DIM + d];
    else if (p == LTXT)      v = text_emb[(size_t)b * DIM + d];
    else if (p == LTXT + 1)  v = time_tab[(size_t)tsteps[b] * DIM + d];
    else                     v = lquery[d];
    x[idx] = v;
}

// ---------------- remapped rel-pos bias with mask baked in ----------------
__global__ void build_biasR(const float* __restrict__ table, float* __restrict__ biasR) {
    int idx = blockIdx.x * 256 + threadIdx.x;
    if (idx >= HEADS * NTOK * 96) return;
    int kap = idx % 96;
    int i = (idx / 96) % NTOK;
    int h = idx / (96 * NTOK);
    float v;
    if ((kap < 80 && kap > i) || kap > 80) {
        v = -1e30f;
    } else {
        int j = (kap < 80) ? kap + 1 : 0;
        int rel = j - i;
        int n = rel < 0 ? -rel : 0;
        int bucket;
        if (n < 16) {
            bucket = n;
        } else {
            float val = logf((float)n / 16.0f) / logf(8.0f) * 16.0f;
            int vl = 16 + (int)val;
            bucket = vl < 31 ? vl : 31;
        }
        v = table[bucket * HEADS + h];
    }
    biasR[idx] = v;
}

// ---------------- weight transpose + f32->bf16: W[K][N] -> WT[N][K] ----------------
__global__ __launch_bounds__(256) void convT(const float* __restrict__ W,
                                             bf16* __restrict__ WT,
                                             int K, int N) {
    __shared__ float t[32][33];
    int n0 = blockIdx.x * 32, k0 = blockIdx.y * 32;
    int tx = threadIdx.x & 31, ty = threadIdx.x >> 5;   // 32 x 8
    #pragma unroll
    for (int i = 0; i < 4; i++)
        t[ty + 8 * i][tx] = W[(size_t)(k0 + ty + 8 * i) * N + n0 + tx];
    __syncthreads();
    #pragma unroll
    for (int i = 0; i < 4; i++)
        WT[(size_t)(n0 + ty + 8 * i) * K + k0 + tx] = __float2bfloat16(t[tx][ty + 8 * i]);
}

// ---------------- rmsnorm, wave-per-row, vectorized ----------------
__global__ __launch_bounds__(256) void rmsnorm_w(const float* __restrict__ x,
                                                 const float* __restrict__ gamma,
                                                 bf16* __restrict__ out) {
    int wave = blockIdx.x * 4 + (threadIdx.x >> 6);
    int lane = threadIdx.x & 63;
    float4 g0 = *(const float4*)&gamma[lane * 4];
    float4 g1 = *(const float4*)&gamma[lane * 4 + 256];
    float4 g2 = *(const float4*)&gamma[lane * 4 + 512];
    #pragma unroll 2
    for (int rr = 0; rr < 8; ++rr) {
        int row = wave * 8 + rr;
        const float* xr = x + (size_t)row * DIM + lane * 4;
        float4 v0 = *(const float4*)xr;
        float4 v1 = *(const float4*)(xr + 256);
        float4 v2 = *(const float4*)(xr + 512);
        float ss = v0.x*v0.x + v0.y*v0.y + v0.z*v0.z + v0.w*v0.w
                 + v1.x*v1.x + v1.y*v1.y + v1.z*v1.z + v1.w*v1.w
                 + v2.x*v2.x + v2.y*v2.y + v2.z*v2.z + v2.w*v2.w;
        #pragma unroll
        for (int o = 32; o > 0; o >>= 1) ss += __shfl_xor(ss, o);
        float inv = 27.712812921102035f / sqrtf(ss + 1e-5f);
        bf16* orow = out + (size_t)row * DIM + lane * 4;
        ushort4 w0 = { f2bf(v0.x*inv*g0.x), f2bf(v0.y*inv*g0.y), f2bf(v0.z*inv*g0.z), f2bf(v0.w*inv*g0.w) };
        ushort4 w1 = { f2bf(v1.x*inv*g1.x), f2bf(v1.y*inv*g1.y), f2bf(v1.z*inv*g1.z), f2bf(v1.w*inv*g1.w) };
        ushort4 w2 = { f2bf(v2.x*inv*g2.x), f2bf(v2.y*inv*g2.y), f2bf(v2.z*inv*g2.z), f2bf(v2.w*inv*g2.w) };
        *(ushort4*)(orow)       = w0;
        *(ushort4*)(orow + 256) = w1;
        *(ushort4*)(orow + 512) = w2;
    }
}

// =========================================================================
// bf16 MFMA GEMMs via global_load_lds, round-6 proven structure (dbuf,
// counted WAITV(8), raw s_barrier, setprio) upgraded to 32x32x16 MFMA:
// half the MFMA instructions, ~+15-20% per-FLOP ceiling, same 64-AGPR acc.
// LDS dest linear; conflict-free via pre-swizzled global source chunk
// (c ^ row&7) + same XOR on fragment read.
// Fragment indices: fr32 = lane&31 (row), hk = lane>>5 (k-half).
// A/B frag (m,kk): lds[row*64 + (((kk*2+hk) ^ (row&7))*8)], row=base+m*32+fr32
// C/D (m74/m101): col = lane&31, row = (reg&3) + 8*(reg>>2) + 4*(lane>>5)
// =========================================================================

#define GSTAGE_N(nld, lds, base, b0, ld, kk0)                                  \
    _Pragma("unroll")                                                          \
    for (int r_ = 0; r_ < (nld); ++r_) {                                       \
        int idx_ = r_ * 256 + t;                                               \
        int row_ = idx_ >> 3, c_ = idx_ & 7;                                   \
        int cs_ = c_ ^ (row_ & 7);                                             \
        __builtin_amdgcn_global_load_lds(                                      \
            (const __attribute__((address_space(1))) unsigned int*)            \
                &base[(size_t)(b0 + row_) * ld + (kk0) + cs_ * 8],             \
            (__attribute__((address_space(3))) unsigned int*)&lds[idx_ * 8],   \
            16, 0, 0);                                                         \
    }

#define FRAG32(lds, base_row, mm, kk)                                          \
    (*(const short8*)&(lds)[((base_row) + (mm) * 32 + fr32) * 64 +             \
        ((((kk) * 2 + hk) ^ (((base_row) + (mm) * 32 + fr32) & 7)) * 8)])

// EPI: 1 = C(f32) += acc ; 2 = C(bf16) = acc
template<int EPI>
__global__ __launch_bounds__(256, 2) void gemm_bt32(const bf16* __restrict__ A,
                                                    const bf16* __restrict__ BT,
                                                    float* __restrict__ C,
                                                    int N, int K) {
    __shared__ __align__(16) short As[2 * 128 * 64];
    __shared__ __align__(16) short Bs[2 * 128 * 64];
    const int t = threadIdx.x;
    const int lane = t & 63;
    const int wid = t >> 6;
    const int wr = wid >> 1, wc = wid & 1;
    const int fr32 = lane & 31;
    const int hk = lane >> 5;
    const int row0 = blockIdx.y * 128, col0 = blockIdx.x * 128;

    f32x16 acc[2][2] = {};
    const int NKT = K >> 6;

    GSTAGE_N(4, As, A, row0, K, 0)
    GSTAGE_N(4, Bs, BT, col0, K, 0)

    for (int kt = 0; kt < NKT; ++kt) {
        const short* curA = As + (kt & 1) * (128 * 64);
        const short* curB = Bs + (kt & 1) * (128 * 64);
        if (kt + 1 < NKT) {
            short* nxtA = As + ((kt + 1) & 1) * (128 * 64);
            short* nxtB = Bs + ((kt + 1) & 1) * (128 * 64);
            int k0n = (kt + 1) << 6;
            GSTAGE_N(4, nxtA, A, row0, K, k0n)
            GSTAGE_N(4, nxtB, BT, col0, K, k0n)
            WAITV(8);       // current tile's 8 loads done; next 8 stay in flight
        } else {
            WAITV(0);
        }
        BARRIER();
        {
            short8 af[2][4], bv[2][4];
            #pragma unroll
            for (int m = 0; m < 2; ++m)
                #pragma unroll
                for (int kk = 0; kk < 4; ++kk)
                    af[m][kk] = FRAG32(curA, wr * 64, m, kk);
            #pragma unroll
            for (int n = 0; n < 2; ++n)
                #pragma unroll
                for (int kk = 0; kk < 4; ++kk)
                    bv[n][kk] = FRAG32(curB, wc * 64, n, kk);
            __builtin_amdgcn_s_setprio(1);
            #pragma unroll
            for (int kk = 0; kk < 4; ++kk)
                #pragma unroll
                for (int m = 0; m < 2; ++m)
                    #pragma unroll
                    for (int n = 0; n < 2; ++n)
                        acc[m][n] = __builtin_amdgcn_mfma_f32_32x32x16_bf16(af[m][kk], bv[n][kk], acc[m][n], 0, 0, 0);
            __builtin_amdgcn_s_setprio(0);
        }
        BARRIER();
    }

    #pragma unroll
    for (int m = 0; m < 2; ++m) {
        #pragma unroll
        for (int n = 0; n < 2; ++n) {
            int brow = row0 + wr * 64 + m * 32 + 4 * hk;
            int col = col0 + wc * 64 + n * 32 + fr32;
            #pragma unroll
            for (int r = 0; r < 16; ++r) {
                int row = brow + (r & 3) + 8 * (r >> 2);
                size_t o = (size_t)row * N + col;
                if (EPI == 1)      C[o] += acc[m][n][r];
                else               ((bf16*)C)[o] = __float2bfloat16(acc[m][n][r]);
            }
        }
    }
}

// =========================================================================
// fused QKV projection: BT = WqkvT [896][768]. Blocks with col0 < 768 write
// q (bf16, stride 768); the col0==768 block splits cols into k (0..63) and
// v (64..127, transposed to vT[b][d][tok]).
// =========================================================================
__global__ __launch_bounds__(256, 2) void gemm_qkv32(const bf16* __restrict__ A,
                                                     const bf16* __restrict__ BT,
                                                     bf16* __restrict__ qb,
                                                     bf16* __restrict__ kout,
                                                     bf16* __restrict__ vT) {
    __shared__ __align__(16) short As[2 * 128 * 64];
    __shared__ __align__(16) short Bs[2 * 128 * 64];
    const int t = threadIdx.x;
    const int lane = t & 63;
    const int wid = t >> 6;
    const int wr = wid >> 1, wc = wid & 1;
    const int fr32 = lane & 31;
    const int hk = lane >> 5;
    const int row0 = blockIdx.y * 128, col0 = blockIdx.x * 128;
    const int K = DIM;

    f32x16 acc[2][2] = {};
    const int NKT = DIM >> 6;

    GSTAGE_N(4, As, A, row0, K, 0)
    GSTAGE_N(4, Bs, BT, col0, K, 0)

    for (int kt = 0; kt < NKT; ++kt) {
        const short* curA = As + (kt & 1) * (128 * 64);
        const short* curB = Bs + (kt & 1) * (128 * 64);
        if (kt + 1 < NKT) {
            short* nxtA = As + ((kt + 1) & 1) * (128 * 64);
            short* nxtB = Bs + ((kt + 1) & 1) * (128 * 64);
            int k0n = (kt + 1) << 6;
            GSTAGE_N(4, nxtA, A, row0, K, k0n)
            GSTAGE_N(4, nxtB, BT, col0, K, k0n)
            WAITV(8);
        } else {
            WAITV(0);
        }
        BARRIER();
        {
            short8 af[2][4], bv[2][4];
            #pragma unroll
            for (int m = 0; m < 2; ++m)
                #pragma unroll
                for (int kk = 0; kk < 4; ++kk)
                    af[m][kk] = FRAG32(curA, wr * 64, m, kk);
            #pragma unroll
            for (int n = 0; n < 2; ++n)
                #pragma unroll
                for (int kk = 0; kk < 4; ++kk)
                    bv[n][kk] = FRAG32(curB, wc * 64, n, kk);
            __builtin_amdgcn_s_setprio(1);
            #pragma unroll
            for (int kk = 0; kk < 4; ++kk)
                #pragma unroll
                for (int m = 0; m < 2; ++m)
                    #pragma unroll
                    for (int n = 0; n < 2; ++n)
                        acc[m][n] = __builtin_amdgcn_mfma_f32_32x32x16_bf16(af[m][kk], bv[n][kk], acc[m][n], 0, 0, 0);
            __builtin_amdgcn_s_setprio(0);
        }
        BARRIER();
    }

    if (col0 < 768) {
        #pragma unroll
        for (int m = 0; m < 2; ++m) {
            #pragma unroll
            for (int n = 0; n < 2; ++n) {
                int brow = row0 + wr * 64 + m * 32 + 4 * hk;
                int col = col0 + wc * 64 + n * 32 + fr32;
                #pragma unroll
                for (int r = 0; r < 16; ++r) {
                    int row = brow + (r & 3) + 8 * (r >> 2);
                    qb[(size_t)row * INNER + col] = __float2bfloat16(acc[m][n][r]);
                }
            }
        }
    } else {
        #pragma unroll
        for (int m = 0; m < 2; ++m) {
            #pragma unroll
            for (int n = 0; n < 2; ++n) {
                int brow = row0 + wr * 64 + m * 32 + 4 * hk;
                int c = wc * 64 + n * 32 + fr32;    // 0..127 local
                #pragma unroll
                for (int r = 0; r < 16; ++r) {
                    int row = brow + (r & 3) + 8 * (r >> 2);
                    float v = acc[m][n][r];
                    if (c < 64) {
                        kout[(size_t)row * 64 + c] = __float2bfloat16(v);
                    } else {
                        int bb = row / NTOK, ii = row - bb * NTOK;
                        vT[((size_t)bb * 64 + (c - 64)) * NTOK + ii] = __float2bfloat16(v);
                    }
                }
            }
        }
    }
}

// =========================================================================
// fused FF1: act = (xn@W1a) * silu(xn@W1g). 128x64 tile (64 a + 64 gate),
// 32x32x16 MFMA, round-6 schedule. acc = 2x(2x1) f32x16 = 64 AGPR.
// =========================================================================
__global__ __launch_bounds__(256, 2) void gemm_ff1_32(const bf16* __restrict__ A,
                                                      const bf16* __restrict__ W1T,
                                                      bf16* __restrict__ act) {
    __shared__ __align__(16) short As[2 * 128 * 64];
    __shared__ __align__(16) short Bs1[2 * 64 * 64];
    __shared__ __align__(16) short Bs2[2 * 64 * 64];
    const int t = threadIdx.x;
    const int lane = t & 63;
    const int wid = t >> 6;
    const int wr = wid >> 1, wc = wid & 1;
    const int fr32 = lane & 31;
    const int hk = lane >> 5;
    const int row0 = blockIdx.y * 128, col0 = blockIdx.x * 64;
    const int K = DIM;
    const bf16* B1 = W1T;
    const bf16* B2 = W1T + (size_t)FFH * DIM;

    f32x16 acc1[2] = {}, acc2[2] = {};
    const int NKT = DIM >> 6;

    GSTAGE_N(4, As, A, row0, K, 0)
    GSTAGE_N(2, Bs1, B1, col0, K, 0)
    GSTAGE_N(2, Bs2, B2, col0, K, 0)

    for (int kt = 0; kt < NKT; ++kt) {
        const short* curA  = As  + (kt & 1) * (128 * 64);
        const short* curB1 = Bs1 + (kt & 1) * (64 * 64);
        const short* curB2 = Bs2 + (kt & 1) * (64 * 64);
        if (kt + 1 < NKT) {
            short* nxtA  = As  + ((kt + 1) & 1) * (128 * 64);
            short* nxtB1 = Bs1 + ((kt + 1) & 1) * (64 * 64);
            short* nxtB2 = Bs2 + ((kt + 1) & 1) * (64 * 64);
            int k0n = (kt + 1) << 6;
            GSTAGE_N(4, nxtA, A, row0, K, k0n)
            GSTAGE_N(2, nxtB1, B1, col0, K, k0n)
            GSTAGE_N(2, nxtB2, B2, col0, K, k0n)
            WAITV(8);
        } else {
            WAITV(0);
        }
        BARRIER();
        {
            short8 af[2][4], b1v[4], b2v[4];
            #pragma unroll
            for (int m = 0; m < 2; ++m)
                #pragma unroll
                for (int kk = 0; kk < 4; ++kk)
                    af[m][kk] = FRAG32(curA, wr * 64, m, kk);
            #pragma unroll
            for (int kk = 0; kk < 4; ++kk) {
                b1v[kk] = FRAG32(curB1, wc * 32, 0, kk);
                b2v[kk] = FRAG32(curB2, wc * 32, 0, kk);
            }
            __builtin_amdgcn_s_setprio(1);
            #pragma unroll
            for (int kk = 0; kk < 4; ++kk)
                #pragma unroll
                for (int m = 0; m < 2; ++m) {
                    acc1[m] = __builtin_amdgcn_mfma_f32_32x32x16_bf16(af[m][kk], b1v[kk], acc1[m], 0, 0, 0);
                    acc2[m] = __builtin_amdgcn_mfma_f32_32x32x16_bf16(af[m][kk], b2v[kk], acc2[m], 0, 0, 0);
                }
            __builtin_amdgcn_s_setprio(0);
        }
        BARRIER();
    }

    #pragma unroll
    for (int m = 0; m < 2; ++m) {
        int brow = row0 + wr * 64 + m * 32 + 4 * hk;
        int col = col0 + wc * 32 + fr32;
        #pragma unroll
        for (int r = 0; r < 16; ++r) {
            int row = brow + (r & 3) + 8 * (r >> 2);
            float a = acc1[m][r];
            float gt = acc2[m][r];
            float s = a * gt / (1.0f + __expf(-gt));
            act[(size_t)row * FFH + col] = __float2bfloat16(s);
        }
    }
}

// =========================================================================
// MFMA attention: one block per (b,h), 4 waves. (unchanged, not hot)
// =========================================================================
__global__ __launch_bounds__(256) void attn_mfma(const bf16* __restrict__ qb,
                                                 const bf16* __restrict__ kbuf,
                                                 const bf16* __restrict__ vT,
                                                 const float* __restrict__ nullkv,  // [2][64] this layer
                                                 const float* __restrict__ biasR,
                                                 bf16* __restrict__ attnb) {
    const int b = blockIdx.x / HEADS;
    const int h = blockIdx.x % HEADS;
    __shared__ __align__(16) short Ks[96 * 64];
    __shared__ __align__(16) short Vt[64 * 128];
    __shared__ __align__(16) float Sls[80 * SROW];
    char* Sb = (char*)Sls;
    const int t = threadIdx.x;
    const int lane = t & 63;
    const int wid = t >> 6;
    const int g = lane >> 4;
    const int fr = lane & 15;

    for (int c = t; c < 768; c += 256) {
        int row = c >> 3, ch = c & 7;
        short8 v;
        if (row < NTOK) {
            v = *(const short8*)&kbuf[((size_t)(b * NTOK + row)) * 64 + ch * 8];
        } else if (row == NTOK) {
            #pragma unroll
            for (int e = 0; e < 8; ++e) v[e] = (short)f2bf(nullkv[ch * 8 + e]);
        } else {
            v = short8{0,0,0,0,0,0,0,0};
        }
        *(short8*)((char*)Ks + row * 128 + ((ch ^ (row & 7)) << 4)) = v;
    }
    for (int c = t; c < 1024; c += 256) {
        int d = c >> 4, ch = c & 15;
        if (ch >= 12) continue;
        short8 v;
        if (ch < 10) {
            v = *(const short8*)&vT[((size_t)b * 64 + d) * NTOK + ch * 8];
        } else if (ch == 10) {
            v = short8{0,0,0,0,0,0,0,0};
            v[0] = (short)f2bf(nullkv[64 + d]);
        } else {
            v = short8{0,0,0,0,0,0,0,0};
        }
        *(short8*)((char*)Vt + d * 256 + ((ch ^ (d & 7)) << 4)) = v;
    }
    __syncthreads();

    const bf16* qbase = qb + ((size_t)(b * NTOK)) * INNER + h * DH;
    for (int s = 0; s < 8; ++s) {
        int tt = wid + 4 * s;
        if (tt >= 30) break;
        int m = tt / 6, n = tt - 6 * m;
        f32x4 acc = {};
        #pragma unroll
        for (int kk = 0; kk < 2; ++kk) {
            short8 a = *(const short8*)&qbase[(size_t)(m * 16 + fr) * INNER + kk * 32 + g * 8];
            int krow = n * 16 + fr;
            short8 kf = *(const short8*)((const char*)Ks + krow * 128 + ((((kk << 2) + g) ^ (krow & 7)) << 4));
            acc = __builtin_amdgcn_mfma_f32_16x16x32_bf16(a, kf, acc, 0, 0, 0);
        }
        int i0 = m * 16 + g * 4;
        int kap = n * 16 + fr;
        const float* bR = biasR + ((size_t)h * NTOK + i0) * 96 + kap;
        #pragma unroll
        for (int r = 0; r < 4; ++r)
            Sls[(i0 + r) * SROW + kap] = acc[r] * 0.125f + bR[r * 96];
    }
    __syncthreads();

    for (int rr = 0; rr < 20; ++rr) {
        int row = wid + 4 * rr;
        const float* Srow = Sls + row * SROW;
        float s0 = Srow[lane];
        float s1v = Srow[64 + (lane & 31)];
        float mx = fmaxf(s0, s1v);
        #pragma unroll
        for (int o = 32; o > 0; o >>= 1) mx = fmaxf(mx, __shfl_xor(mx, o));
        float e0 = __expf(s0 - mx);
        float e1 = (lane < 32) ? __expf(s1v - mx) : 0.0f;
        float sum = e0 + e1;
        #pragma unroll
        for (int o = 32; o > 0; o >>= 1) sum += __shfl_xor(sum, o);
        float inv = 1.0f / sum;
        *(unsigned short*)(Sb + row * (SROW * 4) + lane * 2) = f2bf(e0 * inv);
        if (lane < 32)
            *(unsigned short*)(Sb + row * (SROW * 4) + 128 + lane * 2) = f2bf(e1 * inv);
    }
    __syncthreads();

    for (int s = 0; s < 5; ++s) {
        int tt = wid + 4 * s;
        int m = tt >> 2, n = tt & 3;
        f32x4 acc = {};
        #pragma unroll
        for (int kc = 0; kc < 3; ++kc) {
            short8 p = *(const short8*)(Sb + (m * 16 + fr) * (SROW * 4) + kc * 64 + g * 16);
            int drow = n * 16 + fr;
            short8 vv = *(const short8*)((const char*)Vt + drow * 256 + ((((kc << 2) + g) ^ (drow & 7)) << 4));
            acc = __builtin_amdgcn_mfma_f32_16x16x32_bf16(p, vv, acc, 0, 0, 0);
        }
        int i0 = m * 16 + g * 4;
        int d = n * 16 + fr;
        #pragma unroll
        for (int r = 0; r < 4; ++r)
            attnb[((size_t)(b * NTOK) + i0 + r) * INNER + h * DH + d] = __float2bfloat16(acc[r]);
    }
}

// ---------------- output extraction ----------------
__global__ void extract(const float* __restrict__ x, float* __restrict__ out) {
    int idx = blockIdx.x * 256 + threadIdx.x;
    if (idx >= NB * DIM) return;
    int b = idx / DIM, d = idx % DIM;
    out[idx] = x[((size_t)(b * NTOK + NTOK - 1)) * DIM + d];
}

extern "C" void kernel_launch(void* const* d_in, const int* in_sizes, int n_in,
                              void* d_out, int out_size, void* d_ws, size_t ws_size,
                              hipStream_t stream) {
    (void)in_sizes; (void)n_in; (void)out_size; (void)ws_size;
    const float* text_enc = (const float*)d_in[1];
    const float* text_emb = (const float*)d_in[2];
    const float* time_tab = (const float*)d_in[3];
    const float* lquery   = (const float*)d_in[4];
    const float* rel_tab  = (const float*)d_in[5];
    const float* attn_g   = (const float*)d_in[6];
    const float* Wq       = (const float*)d_in[7];
    const float* Wkv      = (const float*)d_in[8];
    const float* Wout     = (const float*)d_in[9];
    const float* null_kv  = (const float*)d_in[10];
    const float* ff_g     = (const float*)d_in[11];
    const float* Wff1     = (const float*)d_in[12];
    const float* Wff2     = (const float*)d_in[13];
    const int*   tsteps   = (const int*)d_in[14];

    // ---- workspace layout (bytes, all 16-aligned) ----
    char* ws = (char*)d_ws;
    float* x     = (float*)(ws);                        // 62,914,560
    bf16*  xn    = (bf16*)(ws + 62914560);              // 31,457,280 (attn out aliases)
    bf16*  attnb = xn;
    char*  U     = ws + 94371840;                       // union region: 125,829,120
    bf16*  qb    = (bf16*)U;                            //  31,457,280
    bf16*  kbuf  = (bf16*)(U + 31457280);               //   2,621,440
    bf16*  vT    = (bf16*)(U + 34078720);               //   2,621,440
    bf16*  act   = (bf16*)U;                            // 125,829,120 (FF phase)
    float* biasR = (float*)(ws + 220200960);            //     368,640
    bf16*  WqkvT = (bf16*)(ws + 220569600);             //   1,376,256 ([896][768]: q rows 0..767, kv rows 768..895)
    bf16*  WoutT = (bf16*)(ws + 221945856);             //   1,179,648
    bf16*  Wff1T = (bf16*)(ws + 223125504);             //   9,437,184
    bf16*  Wff2T = (bf16*)(ws + 232562688);             //   4,718,592  -> end 237,281,280

    build_tokens<<<(NROWS * DIM + 255) / 256, 256, 0, stream>>>(text_enc, text_emb, time_tab, lquery, tsteps, x);
    build_biasR<<<(HEADS * NTOK * 96 + 255) / 256, 256, 0, stream>>>(rel_tab, biasR);

    for (int l = 0; l < DEPTH; l++) {
        convT<<<dim3(INNER / 32, DIM / 32), 256, 0, stream>>>(Wq   + (size_t)l * DIM * INNER,  WqkvT,               DIM, INNER);
        convT<<<dim3((2 * DH) / 32, DIM / 32), 256, 0, stream>>>(Wkv + (size_t)l * DIM * 2 * DH, WqkvT + 768 * DIM, DIM, 2 * DH);
        convT<<<dim3(DIM / 32, INNER / 32), 256, 0, stream>>>(Wout + (size_t)l * INNER * DIM,  WoutT, INNER, DIM);
        convT<<<dim3(FF2C / 32, DIM / 32), 256, 0, stream>>>(Wff1 + (size_t)l * DIM * FF2C,    Wff1T, DIM,   FF2C);
        convT<<<dim3(DIM / 32, FFH / 32), 256, 0, stream>>>(Wff2  + (size_t)l * FFH * DIM,     Wff2T, FFH,   DIM);

        // ---- attention block ----
        rmsnorm_w<<<NROWS / (8 * 4), 256, 0, stream>>>(x, attn_g + (size_t)l * DIM, xn);
        gemm_qkv32<<<dim3(896 / 128, NROWS / 128), 256, 0, stream>>>(xn, WqkvT, qb, kbuf, vT);
        attn_mfma<<<NB * HEADS, 256, 0, stream>>>(qb, kbuf, vT, null_kv + (size_t)l * 2 * DH, biasR, attnb);
        gemm_bt32<1><<<dim3(DIM / 128, NROWS / 128), 256, 0, stream>>>(attnb, WoutT, x, DIM, INNER);

        // ---- feedforward block ----
        rmsnorm_w<<<NROWS / (8 * 4), 256, 0, stream>>>(x, ff_g + (size_t)l * DIM, xn);
        gemm_ff1_32<<<dim3(FFH / 64, NROWS / 128), 256, 0, stream>>>(xn, Wff1T, act);
        gemm_bt32<1><<<dim3(DIM / 128, NROWS / 128), 256, 0, stream>>>(act, Wff2T, x, DIM, FFH);
    }

    extract<<<(NB * DIM + 255) / 256, 256, 0, stream>>>(x, (float*)d_out);
}

// Round 9
// 7427.082 us; speedup vs baseline: 1.1237x; 1.1237x over previous
//
#include <hip/hip_runtime.h>
#include <hip/hip_bf16.h>
#include <float.h>
#include <math.h>

#define NB 256
#define LTXT 77
#define DIM 768
#define DEPTH 12
#define HEADS 12
#define DH 64
#define NTOK 80
#define NKEY 81
#define NROWS (NB*NTOK)       // 20480
#define FFH 3072
#define FF2C 6144
#define INNER 768
#define SROW 100              // f32 per S row (mod-32 = 4 -> 2-way banks)

typedef __hip_bfloat16 bf16;
typedef __attribute__((ext_vector_type(8))) short short8;
typedef __attribute__((ext_vector_type(4))) float f32x4;

#define BARRIER() asm volatile("s_barrier" ::: "memory")
#define WAITV(n)  asm volatile("s_waitcnt vmcnt(" #n ")" ::: "memory")

__device__ __forceinline__ unsigned short f2bf(float f) {
    __hip_bfloat16 h = __float2bfloat16(f);
    return __builtin_bit_cast(unsigned short, h);
}

// ---------------- token build ----------------
__global__ void build_tokens(const float* __restrict__ text_enc,
                             const float* __restrict__ text_emb,
                             const float* __restrict__ time_tab,
                             const float* __restrict__ lquery,
                             const int* __restrict__ tsteps,
                             float* __restrict__ x) {
    int idx = blockIdx.x * 256 + threadIdx.x;
    if (idx >= NROWS * DIM) return;
    int d = idx % DIM;
    int row = idx / DIM;
    int b = row / NTOK, p = row % NTOK;
    float v;
    if (p < LTXT)            v = text_enc[((size_t)b * LTXT + p) * DIM + d];
    else if (p == LTXT)      v = text_emb[(size_t)b * DIM + d];
    else if (p == LTXT + 1)  v = time_tab[(size_t)tsteps[b] * DIM + d];
    else                     v = lquery[d];
    x[idx] = v;
}

// ---------------- remapped rel-pos bias with mask baked in ----------------
__global__ void build_biasR(const float* __restrict__ table, float* __restrict__ biasR) {
    int idx = blockIdx.x * 256 + threadIdx.x;
    if (idx >= HEADS * NTOK * 96) return;
    int kap = idx % 96;
    int i = (idx / 96) % NTOK;
    int h = idx / (96 * NTOK);
    float v;
    if ((kap < 80 && kap > i) || kap > 80) {
        v = -1e30f;
    } else {
        int j = (kap < 80) ? kap + 1 : 0;
        int rel = j - i;
        int n = rel < 0 ? -rel : 0;
        int bucket;
        if (n < 16) {
            bucket = n;
        } else {
            float val = logf((float)n / 16.0f) / logf(8.0f) * 16.0f;
            int vl = 16 + (int)val;
            bucket = vl < 31 ? vl : 31;
        }
        v = table[bucket * HEADS + h];
    }
    biasR[idx] = v;
}

// ---------------- merged weight transpose+convert: 1 dispatch per layer ----------------
// segments (32x32 tiles): Wq->WqkvT[0:768), Wkv->WqkvT[768:896), Wout->WoutT,
// Wff1->Wff1T, Wff2->Wff2T.   WT[n*K + k] = bf16(W[k*N + n])
__global__ __launch_bounds__(256) void convT_all(const float* __restrict__ Wq,
                                                 const float* __restrict__ Wkv,
                                                 const float* __restrict__ Wout,
                                                 const float* __restrict__ Wff1,
                                                 const float* __restrict__ Wff2,
                                                 bf16* __restrict__ WqkvT,
                                                 bf16* __restrict__ WoutT,
                                                 bf16* __restrict__ Wff1T,
                                                 bf16* __restrict__ Wff2T) {
    int bid = blockIdx.x;
    const float* W; bf16* WT; int K, N, local;
    if (bid < 576)       { W = Wq;   WT = WqkvT;             K = 768;  N = 768;  local = bid; }
    else if (bid < 672)  { W = Wkv;  WT = WqkvT + 768 * 768; K = 768;  N = 128;  local = bid - 576; }
    else if (bid < 1248) { W = Wout; WT = WoutT;             K = 768;  N = 768;  local = bid - 672; }
    else if (bid < 5856) { W = Wff1; WT = Wff1T;             K = 768;  N = 6144; local = bid - 1248; }
    else                 { W = Wff2; WT = Wff2T;             K = 3072; N = 768;  local = bid - 5856; }
    int nblk = N / 32;
    int n0 = (local % nblk) * 32, k0 = (local / nblk) * 32;

    __shared__ float tt[32][33];
    int tx = threadIdx.x & 31, ty = threadIdx.x >> 5;   // 32 x 8
    #pragma unroll
    for (int i = 0; i < 4; i++)
        tt[ty + 8 * i][tx] = W[(size_t)(k0 + ty + 8 * i) * N + n0 + tx];
    __syncthreads();
    #pragma unroll
    for (int i = 0; i < 4; i++)
        WT[(size_t)(n0 + ty + 8 * i) * K + k0 + tx] = __float2bfloat16(tt[tx][ty + 8 * i]);
}

// ---------------- rmsnorm, wave-per-row, vectorized ----------------
__global__ __launch_bounds__(256) void rmsnorm_w(const float* __restrict__ x,
                                                 const float* __restrict__ gamma,
                                                 bf16* __restrict__ out) {
    int wave = blockIdx.x * 4 + (threadIdx.x >> 6);
    int lane = threadIdx.x & 63;
    float4 g0 = *(const float4*)&gamma[lane * 4];
    float4 g1 = *(const float4*)&gamma[lane * 4 + 256];
    float4 g2 = *(const float4*)&gamma[lane * 4 + 512];
    #pragma unroll 2
    for (int rr = 0; rr < 8; ++rr) {
        int row = wave * 8 + rr;
        const float* xr = x + (size_t)row * DIM + lane * 4;
        float4 v0 = *(const float4*)xr;
        float4 v1 = *(const float4*)(xr + 256);
        float4 v2 = *(const float4*)(xr + 512);
        float ss = v0.x*v0.x + v0.y*v0.y + v0.z*v0.z + v0.w*v0.w
                 + v1.x*v1.x + v1.y*v1.y + v1.z*v1.z + v1.w*v1.w
                 + v2.x*v2.x + v2.y*v2.y + v2.z*v2.z + v2.w*v2.w;
        #pragma unroll
        for (int o = 32; o > 0; o >>= 1) ss += __shfl_xor(ss, o);
        float inv = 27.712812921102035f / sqrtf(ss + 1e-5f);
        bf16* orow = out + (size_t)row * DIM + lane * 4;
        ushort4 w0 = { f2bf(v0.x*inv*g0.x), f2bf(v0.y*inv*g0.y), f2bf(v0.z*inv*g0.z), f2bf(v0.w*inv*g0.w) };
        ushort4 w1 = { f2bf(v1.x*inv*g1.x), f2bf(v1.y*inv*g1.y), f2bf(v1.z*inv*g1.z), f2bf(v1.w*inv*g1.w) };
        ushort4 w2 = { f2bf(v2.x*inv*g2.x), f2bf(v2.y*inv*g2.y), f2bf(v2.z*inv*g2.z), f2bf(v2.w*inv*g2.w) };
        *(ushort4*)(orow)       = w0;
        *(ushort4*)(orow + 256) = w1;
        *(ushort4*)(orow + 512) = w2;
    }
}

// rmsnorm for last layer: only rows i*80+79 (256 rows), compact output
__global__ __launch_bounds__(256) void rmsnorm_last(const float* __restrict__ x,
                                                    const float* __restrict__ gamma,
                                                    bf16* __restrict__ out) {
    int wave = blockIdx.x * 4 + (threadIdx.x >> 6);
    int lane = threadIdx.x & 63;
    float4 g0 = *(const float4*)&gamma[lane * 4];
    float4 g1 = *(const float4*)&gamma[lane * 4 + 256];
    float4 g2 = *(const float4*)&gamma[lane * 4 + 512];
    #pragma unroll 2
    for (int rr = 0; rr < 8; ++rr) {
        int row = wave * 8 + rr;                       // 0..255 (batch index)
        const float* xr = x + ((size_t)row * NTOK + 79) * DIM + lane * 4;
        float4 v0 = *(const float4*)xr;
        float4 v1 = *(const float4*)(xr + 256);
        float4 v2 = *(const float4*)(xr + 512);
        float ss = v0.x*v0.x + v0.y*v0.y + v0.z*v0.z + v0.w*v0.w
                 + v1.x*v1.x + v1.y*v1.y + v1.z*v1.z + v1.w*v1.w
                 + v2.x*v2.x + v2.y*v2.y + v2.z*v2.z + v2.w*v2.w;
        #pragma unroll
        for (int o = 32; o > 0; o >>= 1) ss += __shfl_xor(ss, o);
        float inv = 27.712812921102035f / sqrtf(ss + 1e-5f);
        bf16* orow = out + (size_t)row * DIM + lane * 4;
        ushort4 w0 = { f2bf(v0.x*inv*g0.x), f2bf(v0.y*inv*g0.y), f2bf(v0.z*inv*g0.z), f2bf(v0.w*inv*g0.w) };
        ushort4 w1 = { f2bf(v1.x*inv*g1.x), f2bf(v1.y*inv*g1.y), f2bf(v1.z*inv*g1.z), f2bf(v1.w*inv*g1.w) };
        ushort4 w2 = { f2bf(v2.x*inv*g2.x), f2bf(v2.y*inv*g2.y), f2bf(v2.z*inv*g2.z), f2bf(v2.w*inv*g2.w) };
        *(ushort4*)(orow)       = w0;
        *(ushort4*)(orow + 256) = w1;
        *(ushort4*)(orow + 512) = w2;
    }
}

// =========================================================================
// bf16 MFMA GEMM via global_load_lds, round-6 proven structure: 128x128,
// 16x16x32 MFMA, dbuf, counted WAITV(8), raw s_barrier, setprio.
// LDS dest linear; conflict-free via pre-swizzled global source chunk
// (c ^ row&7) + same XOR on fragment read (2-way bank aliasing = free).
// =========================================================================

#define GSTAGE_N(nld, lds, base, b0, ld, kk0)                                  \
    _Pragma("unroll")                                                          \
    for (int r_ = 0; r_ < (nld); ++r_) {                                       \
        int idx_ = r_ * 256 + t;                                               \
        int row_ = idx_ >> 3, c_ = idx_ & 7;                                   \
        int cs_ = c_ ^ (row_ & 7);                                             \
        __builtin_amdgcn_global_load_lds(                                      \
            (const __attribute__((address_space(1))) unsigned int*)            \
                &base[(size_t)(b0 + row_) * (ld) + (kk0) + cs_ * 8],           \
            (__attribute__((address_space(3))) unsigned int*)&lds[idx_ * 8],   \
            16, 0, 0);                                                         \
    }

#define FRAG_READ(dst, lds, base_row, kk)                                      \
    _Pragma("unroll")                                                          \
    for (int q_ = 0; q_ < 4; ++q_) {                                           \
        int row_ = (base_row) + q_ * 16 + fr;                                  \
        int ch_ = ((((kk) << 2) + kb) ^ (row_ & 7));                           \
        dst[q_] = *(const short8*)&lds[row_ * 64 + ch_ * 8];                   \
    }

#define FRAG_READ2(dst, lds, base_row, kk)                                     \
    _Pragma("unroll")                                                          \
    for (int q_ = 0; q_ < 2; ++q_) {                                           \
        int row_ = (base_row) + q_ * 16 + fr;                                  \
        int ch_ = ((((kk) << 2) + kb) ^ (row_ & 7));                           \
        dst[q_] = *(const short8*)&lds[row_ * 64 + ch_ * 8];                   \
    }

// EPI: 1 = C(f32) += acc. lda = A row stride, ldc = C row stride (elements).
template<int EPI>
__global__ __launch_bounds__(256, 2) void gemm_bt(const bf16* __restrict__ A,
                                                  const bf16* __restrict__ BT,
                                                  float* __restrict__ C,
                                                  int N, int K, int lda, int ldc) {
    __shared__ __align__(16) short As[2 * 128 * 64];
    __shared__ __align__(16) short Bs[2 * 128 * 64];
    const int t = threadIdx.x;
    const int lane = t & 63;
    const int wid = t >> 6;
    const int wr = wid >> 1, wc = wid & 1;
    const int fr = lane & 15;
    const int kb = lane >> 4;
    const int row0 = blockIdx.y * 128, col0 = blockIdx.x * 128;

    f32x4 acc[4][4] = {};
    const int NKT = K >> 6;

    GSTAGE_N(4, As, A, row0, lda, 0)
    GSTAGE_N(4, Bs, BT, col0, K, 0)

    for (int kt = 0; kt < NKT; ++kt) {
        const short* curA = As + (kt & 1) * (128 * 64);
        const short* curB = Bs + (kt & 1) * (128 * 64);
        if (kt + 1 < NKT) {
            short* nxtA = As + ((kt + 1) & 1) * (128 * 64);
            short* nxtB = Bs + ((kt + 1) & 1) * (128 * 64);
            int k0n = (kt + 1) << 6;
            GSTAGE_N(4, nxtA, A, row0, lda, k0n)
            GSTAGE_N(4, nxtB, BT, col0, K, k0n)
            WAITV(8);       // current tile's 8 loads done; next 8 stay in flight
        } else {
            WAITV(0);
        }
        BARRIER();
        #pragma unroll
        for (int kk = 0; kk < 2; ++kk) {
            short8 af[4], bv[4];
            FRAG_READ(af, curA, wr * 64, kk)
            FRAG_READ(bv, curB, wc * 64, kk)
            __builtin_amdgcn_s_setprio(1);
            #pragma unroll
            for (int i = 0; i < 4; ++i)
                #pragma unroll
                for (int j = 0; j < 4; ++j)
                    acc[i][j] = __builtin_amdgcn_mfma_f32_16x16x32_bf16(af[i], bv[j], acc[i][j], 0, 0, 0);
            __builtin_amdgcn_s_setprio(0);
        }
        BARRIER();
    }

    #pragma unroll
    for (int i = 0; i < 4; ++i) {
        #pragma unroll
        for (int j = 0; j < 4; ++j) {
            int row = row0 + wr * 64 + i * 16 + kb * 4;
            int col = col0 + wc * 64 + j * 16 + fr;
            #pragma unroll
            for (int r = 0; r < 4; ++r) {
                size_t o = (size_t)(row + r) * ldc + col;
                C[o] += acc[i][j][r];
            }
        }
    }
}

// =========================================================================
// fused QKV: BT = WqkvT [896][768]. col0<768 -> q (bf16, stride INNER);
// col0==768 block: wc==0 -> k[row][64], wc==1 -> vT[b][d][tok].
// =========================================================================
__global__ __launch_bounds__(256, 2) void gemm_qkv(const bf16* __restrict__ A,
                                                   const bf16* __restrict__ BT,
                                                   bf16* __restrict__ qb,
                                                   bf16* __restrict__ kout,
                                                   bf16* __restrict__ vT) {
    __shared__ __align__(16) short As[2 * 128 * 64];
    __shared__ __align__(16) short Bs[2 * 128 * 64];
    const int t = threadIdx.x;
    const int lane = t & 63;
    const int wid = t >> 6;
    const int wr = wid >> 1, wc = wid & 1;
    const int fr = lane & 15;
    const int kb = lane >> 4;
    const int row0 = blockIdx.y * 128, col0 = blockIdx.x * 128;
    const int K = DIM;

    f32x4 acc[4][4] = {};
    const int NKT = DIM >> 6;

    GSTAGE_N(4, As, A, row0, K, 0)
    GSTAGE_N(4, Bs, BT, col0, K, 0)

    for (int kt = 0; kt < NKT; ++kt) {
        const short* curA = As + (kt & 1) * (128 * 64);
        const short* curB = Bs + (kt & 1) * (128 * 64);
        if (kt + 1 < NKT) {
            short* nxtA = As + ((kt + 1) & 1) * (128 * 64);
            short* nxtB = Bs + ((kt + 1) & 1) * (128 * 64);
            int k0n = (kt + 1) << 6;
            GSTAGE_N(4, nxtA, A, row0, K, k0n)
            GSTAGE_N(4, nxtB, BT, col0, K, k0n)
            WAITV(8);
        } else {
            WAITV(0);
        }
        BARRIER();
        #pragma unroll
        for (int kk = 0; kk < 2; ++kk) {
            short8 af[4], bv[4];
            FRAG_READ(af, curA, wr * 64, kk)
            FRAG_READ(bv, curB, wc * 64, kk)
            __builtin_amdgcn_s_setprio(1);
            #pragma unroll
            for (int i = 0; i < 4; ++i)
                #pragma unroll
                for (int j = 0; j < 4; ++j)
                    acc[i][j] = __builtin_amdgcn_mfma_f32_16x16x32_bf16(af[i], bv[j], acc[i][j], 0, 0, 0);
            __builtin_amdgcn_s_setprio(0);
        }
        BARRIER();
    }

    if (col0 < 768) {
        #pragma unroll
        for (int i = 0; i < 4; ++i) {
            #pragma unroll
            for (int j = 0; j < 4; ++j) {
                int row = row0 + wr * 64 + i * 16 + kb * 4;
                int col = col0 + wc * 64 + j * 16 + fr;
                #pragma unroll
                for (int r = 0; r < 4; ++r)
                    qb[(size_t)(row + r) * INNER + col] = __float2bfloat16(acc[i][j][r]);
            }
        }
    } else {
        #pragma unroll
        for (int i = 0; i < 4; ++i) {
            #pragma unroll
            for (int j = 0; j < 4; ++j) {
                int row = row0 + wr * 64 + i * 16 + kb * 4;
                int col = wc * 64 + j * 16 + fr;   // 0..127 local
                #pragma unroll
                for (int r = 0; r < 4; ++r) {
                    int rg = row + r;
                    float v = acc[i][j][r];
                    if (wc == 0) {
                        kout[(size_t)rg * 64 + col] = __float2bfloat16(v);
                    } else {
                        int bb = rg / NTOK, ii = rg - bb * NTOK;
                        vT[((size_t)bb * 64 + (col - 64)) * NTOK + ii] = __float2bfloat16(v);
                    }
                }
            }
        }
    }
}

// =========================================================================
// fused FF1: act = (A@W1a) * silu(A@W1g). 128x64 tile, round-6 schedule.
// A has row stride DIM (both full M and compact M=256 paths).
// =========================================================================
__global__ __launch_bounds__(256, 2) void gemm_ff1(const bf16* __restrict__ A,
                                                   const bf16* __restrict__ W1T,
                                                   bf16* __restrict__ act) {
    __shared__ __align__(16) short As[2 * 128 * 64];
    __shared__ __align__(16) short Bs1[2 * 64 * 64];
    __shared__ __align__(16) short Bs2[2 * 64 * 64];
    const int t = threadIdx.x;
    const int lane = t & 63;
    const int wid = t >> 6;
    const int wr = wid >> 1, wc = wid & 1;
    const int fr = lane & 15;
    const int kb = lane >> 4;
    const int row0 = blockIdx.y * 128, col0 = blockIdx.x * 64;
    const int K = DIM;
    const bf16* B1 = W1T;
    const bf16* B2 = W1T + (size_t)FFH * DIM;

    f32x4 acc1[4][2] = {}, acc2[4][2] = {};
    const int NKT = DIM >> 6;

    GSTAGE_N(4, As, A, row0, K, 0)
    GSTAGE_N(2, Bs1, B1, col0, K, 0)
    GSTAGE_N(2, Bs2, B2, col0, K, 0)

    for (int kt = 0; kt < NKT; ++kt) {
        const short* curA  = As  + (kt & 1) * (128 * 64);
        const short* curB1 = Bs1 + (kt & 1) * (64 * 64);
        const short* curB2 = Bs2 + (kt & 1) * (64 * 64);
        if (kt + 1 < NKT) {
            short* nxtA  = As  + ((kt + 1) & 1) * (128 * 64);
            short* nxtB1 = Bs1 + ((kt + 1) & 1) * (64 * 64);
            short* nxtB2 = Bs2 + ((kt + 1) & 1) * (64 * 64);
            int k0n = (kt + 1) << 6;
            GSTAGE_N(4, nxtA, A, row0, K, k0n)
            GSTAGE_N(2, nxtB1, B1, col0, K, k0n)
            GSTAGE_N(2, nxtB2, B2, col0, K, k0n)
            WAITV(8);       // current tile's 8 loads done; next 8 in flight
        } else {
            WAITV(0);
        }
        BARRIER();
        #pragma unroll
        for (int kk = 0; kk < 2; ++kk) {
            short8 af[4], b1v[2], b2v[2];
            FRAG_READ(af, curA, wr * 64, kk)
            FRAG_READ2(b1v, curB1, wc * 32, kk)
            FRAG_READ2(b2v, curB2, wc * 32, kk)
            __builtin_amdgcn_s_setprio(1);
            #pragma unroll
            for (int i = 0; i < 4; ++i)
                #pragma unroll
                for (int j = 0; j < 2; ++j) {
                    acc1[i][j] = __builtin_amdgcn_mfma_f32_16x16x32_bf16(af[i], b1v[j], acc1[i][j], 0, 0, 0);
                    acc2[i][j] = __builtin_amdgcn_mfma_f32_16x16x32_bf16(af[i], b2v[j], acc2[i][j], 0, 0, 0);
                }
            __builtin_amdgcn_s_setprio(0);
        }
        BARRIER();
    }

    #pragma unroll
    for (int i = 0; i < 4; ++i) {
        #pragma unroll
        for (int j = 0; j < 2; ++j) {
            int row = row0 + wr * 64 + i * 16 + kb * 4;
            int col = col0 + wc * 32 + j * 16 + fr;
            #pragma unroll
            for (int r = 0; r < 4; ++r) {
                float a = acc1[i][j][r];
                float gt = acc2[i][j][r];
                float s = a * gt / (1.0f + __expf(-gt));
                act[(size_t)(row + r) * FFH + col] = __float2bfloat16(s);
            }
        }
    }
}

// =========================================================================
// MFMA attention: one block per (b,h), 4 waves. (unchanged)
// =========================================================================
__global__ __launch_bounds__(256) void attn_mfma(const bf16* __restrict__ qb,
                                                 const bf16* __restrict__ kbuf,
                                                 const bf16* __restrict__ vT,
                                                 const float* __restrict__ nullkv,  // [2][64] this layer
                                                 const float* __restrict__ biasR,
                                                 bf16* __restrict__ attnb) {
    const int b = blockIdx.x / HEADS;
    const int h = blockIdx.x % HEADS;
    __shared__ __align__(16) short Ks[96 * 64];
    __shared__ __align__(16) short Vt[64 * 128];
    __shared__ __align__(16) float Sls[80 * SROW];
    char* Sb = (char*)Sls;
    const int t = threadIdx.x;
    const int lane = t & 63;
    const int wid = t >> 6;
    const int g = lane >> 4;
    const int fr = lane & 15;

    for (int c = t; c < 768; c += 256) {
        int row = c >> 3, ch = c & 7;
        short8 v;
        if (row < NTOK) {
            v = *(const short8*)&kbuf[((size_t)(b * NTOK + row)) * 64 + ch * 8];
        } else if (row == NTOK) {
            #pragma unroll
            for (int e = 0; e < 8; ++e) v[e] = (short)f2bf(nullkv[ch * 8 + e]);
        } else {
            v = short8{0,0,0,0,0,0,0,0};
        }
        *(short8*)((char*)Ks + row * 128 + ((ch ^ (row & 7)) << 4)) = v;
    }
    for (int c = t; c < 1024; c += 256) {
        int d = c >> 4, ch = c & 15;
        if (ch >= 12) continue;
        short8 v;
        if (ch < 10) {
            v = *(const short8*)&vT[((size_t)b * 64 + d) * NTOK + ch * 8];
        } else if (ch == 10) {
            v = short8{0,0,0,0,0,0,0,0};
            v[0] = (short)f2bf(nullkv[64 + d]);
        } else {
            v = short8{0,0,0,0,0,0,0,0};
        }
        *(short8*)((char*)Vt + d * 256 + ((ch ^ (d & 7)) << 4)) = v;
    }
    __syncthreads();

    const bf16* qbase = qb + ((size_t)(b * NTOK)) * INNER + h * DH;
    for (int s = 0; s < 8; ++s) {
        int tt = wid + 4 * s;
        if (tt >= 30) break;
        int m = tt / 6, n = tt - 6 * m;
        f32x4 acc = {};
        #pragma unroll
        for (int kk = 0; kk < 2; ++kk) {
            short8 a = *(const short8*)&qbase[(size_t)(m * 16 + fr) * INNER + kk * 32 + g * 8];
            int krow = n * 16 + fr;
            short8 kf = *(const short8*)((const char*)Ks + krow * 128 + ((((kk << 2) + g) ^ (krow & 7)) << 4));
            acc = __builtin_amdgcn_mfma_f32_16x16x32_bf16(a, kf, acc, 0, 0, 0);
        }
        int i0 = m * 16 + g * 4;
        int kap = n * 16 + fr;
        const float* bR = biasR + ((size_t)h * NTOK + i0) * 96 + kap;
        #pragma unroll
        for (int r = 0; r < 4; ++r)
            Sls[(i0 + r) * SROW + kap] = acc[r] * 0.125f + bR[r * 96];
    }
    __syncthreads();

    for (int rr = 0; rr < 20; ++rr) {
        int row = wid + 4 * rr;
        const float* Srow = Sls + row * SROW;
        float s0 = Srow[lane];
        float s1v = Srow[64 + (lane & 31)];
        float mx = fmaxf(s0, s1v);
        #pragma unroll
        for (int o = 32; o > 0; o >>= 1) mx = fmaxf(mx, __shfl_xor(mx, o));
        float e0 = __expf(s0 - mx);
        float e1 = (lane < 32) ? __expf(s1v - mx) : 0.0f;
        float sum = e0 + e1;
        #pragma unroll
        for (int o = 32; o > 0; o >>= 1) sum += __shfl_xor(sum, o);
        float inv = 1.0f / sum;
        *(unsigned short*)(Sb + row * (SROW * 4) + lane * 2) = f2bf(e0 * inv);
        if (lane < 32)
            *(unsigned short*)(Sb + row * (SROW * 4) + 128 + lane * 2) = f2bf(e1 * inv);
    }
    __syncthreads();

    for (int s = 0; s < 5; ++s) {
        int tt = wid + 4 * s;
        int m = tt >> 2, n = tt & 3;
        f32x4 acc = {};
        #pragma unroll
        for (int kc = 0; kc < 3; ++kc) {
            short8 p = *(const short8*)(Sb + (m * 16 + fr) * (SROW * 4) + kc * 64 + g * 16);
            int drow = n * 16 + fr;
            short8 vv = *(const short8*)((const char*)Vt + drow * 256 + ((((kc << 2) + g) ^ (drow & 7)) << 4));
            acc = __builtin_amdgcn_mfma_f32_16x16x32_bf16(p, vv, acc, 0, 0, 0);
        }
        int i0 = m * 16 + g * 4;
        int d = n * 16 + fr;
        #pragma unroll
        for (int r = 0; r < 4; ++r)
            attnb[((size_t)(b * NTOK) + i0 + r) * INNER + h * DH + d] = __float2bfloat16(acc[r]);
    }
}

// ---------------- output extraction ----------------
__global__ void extract(const float* __restrict__ x, float* __restrict__ out) {
    int idx = blockIdx.x * 256 + threadIdx.x;
    if (idx >= NB * DIM) return;
    int b = idx / DIM, d = idx % DIM;
    out[idx] = x[((size_t)(b * NTOK + NTOK - 1)) * DIM + d];
}

extern "C" void kernel_launch(void* const* d_in, const int* in_sizes, int n_in,
                              void* d_out, int out_size, void* d_ws, size_t ws_size,
                              hipStream_t stream) {
    (void)in_sizes; (void)n_in; (void)out_size; (void)ws_size;
    const float* text_enc = (const float*)d_in[1];
    const float* text_emb = (const float*)d_in[2];
    const float* time_tab = (const float*)d_in[3];
    const float* lquery   = (const float*)d_in[4];
    const float* rel_tab  = (const float*)d_in[5];
    const float* attn_g   = (const float*)d_in[6];
    const float* Wq       = (const float*)d_in[7];
    const float* Wkv      = (const float*)d_in[8];
    const float* Wout     = (const float*)d_in[9];
    const float* null_kv  = (const float*)d_in[10];
    const float* ff_g     = (const float*)d_in[11];
    const float* Wff1     = (const float*)d_in[12];
    const float* Wff2     = (const float*)d_in[13];
    const int*   tsteps   = (const int*)d_in[14];

    // ---- workspace layout (bytes, all 16-aligned) ----
    char* ws = (char*)d_ws;
    float* x     = (float*)(ws);                        // 62,914,560
    bf16*  xn    = (bf16*)(ws + 62914560);              // 31,457,280 (attn out aliases)
    bf16*  attnb = xn;
    char*  U     = ws + 94371840;                       // union region: 125,829,120
    bf16*  qb    = (bf16*)U;                            //  31,457,280
    bf16*  kbuf  = (bf16*)(U + 31457280);               //   2,621,440
    bf16*  vT    = (bf16*)(U + 34078720);               //   2,621,440
    bf16*  act   = (bf16*)U;                            // 125,829,120 (FF phase)
    float* biasR = (float*)(ws + 220200960);            //     368,640
    bf16*  WqkvT = (bf16*)(ws + 220569600);             //   1,376,256 ([896][768])
    bf16*  WoutT = (bf16*)(ws + 221945856);             //   1,179,648
    bf16*  Wff1T = (bf16*)(ws + 223125504);             //   9,437,184
    bf16*  Wff2T = (bf16*)(ws + 232562688);             //   4,718,592  -> end 237,281,280

    build_tokens<<<(NROWS * DIM + 255) / 256, 256, 0, stream>>>(text_enc, text_emb, time_tab, lquery, tsteps, x);
    build_biasR<<<(HEADS * NTOK * 96 + 255) / 256, 256, 0, stream>>>(rel_tab, biasR);

    for (int l = 0; l < DEPTH; l++) {
        convT_all<<<8160, 256, 0, stream>>>(Wq   + (size_t)l * DIM * INNER,
                                            Wkv  + (size_t)l * DIM * 2 * DH,
                                            Wout + (size_t)l * INNER * DIM,
                                            Wff1 + (size_t)l * DIM * FF2C,
                                            Wff2 + (size_t)l * FFH * DIM,
                                            WqkvT, WoutT, Wff1T, Wff2T);

        // ---- attention block ----
        rmsnorm_w<<<NROWS / 32, 256, 0, stream>>>(x, attn_g + (size_t)l * DIM, xn);
        gemm_qkv<<<dim3(7, NROWS / 128), 256, 0, stream>>>(xn, WqkvT, qb, kbuf, vT);
        attn_mfma<<<NB * HEADS, 256, 0, stream>>>(qb, kbuf, vT, null_kv + (size_t)l * 2 * DH, biasR, attnb);

        if (l < DEPTH - 1) {
            gemm_bt<1><<<dim3(DIM / 128, NROWS / 128), 256, 0, stream>>>(attnb, WoutT, x, DIM, INNER, INNER, DIM);
            // ---- feedforward block ----
            rmsnorm_w<<<NROWS / 32, 256, 0, stream>>>(x, ff_g + (size_t)l * DIM, xn);
            gemm_ff1<<<dim3(FFH / 64, NROWS / 128), 256, 0, stream>>>(xn, Wff1T, act);
            gemm_bt<1><<<dim3(DIM / 128, NROWS / 128), 256, 0, stream>>>(act, Wff2T, x, DIM, FFH, FFH, DIM);
        } else {
            // ---- last layer: only token 79 per batch feeds the output ----
            gemm_bt<1><<<dim3(DIM / 128, 2), 256, 0, stream>>>(
                attnb + (size_t)79 * INNER, WoutT, x + (size_t)79 * DIM,
                DIM, INNER, NTOK * INNER, NTOK * DIM);
            rmsnorm_last<<<8, 256, 0, stream>>>(x, ff_g + (size_t)l * DIM, xn);
            gemm_ff1<<<dim3(FFH / 64, 2), 256, 0, stream>>>(xn, Wff1T, act);
            gemm_bt<1><<<dim3(DIM / 128, 2), 256, 0, stream>>>(
                act, Wff2T, x + (size_t)79 * DIM,
                DIM, FFH, FFH, NTOK * DIM);
        }
    }

    extract<<<(NB * DIM + 255) / 256, 256, 0, stream>>>(x, (float*)d_out);
}

// Round 10
// 7407.330 us; speedup vs baseline: 1.1267x; 1.0027x over previous
//
#include <hip/hip_runtime.h>
#include <hip/hip_bf16.h>
#include <float.h>
#include <math.h>

#define NB 256
#define LTXT 77
#define DIM 768
#define DEPTH 12
#define HEADS 12
#define DH 64
#define NTOK 80
#define NKEY 81
#define NROWS (NB*NTOK)       // 20480
#define FFH 3072
#define FF2C 6144
#define INNER 768
#define SROW 100              // f32 per S row (mod-32 = 4 -> 2-way banks)

typedef __hip_bfloat16 bf16;
typedef __attribute__((ext_vector_type(8))) short short8;
typedef __attribute__((ext_vector_type(4))) float f32x4;

#define BARRIER() asm volatile("s_barrier" ::: "memory")
#define WAITV(n)  asm volatile("s_waitcnt vmcnt(" #n ")" ::: "memory")

__device__ __forceinline__ unsigned short f2bf(float f) {
    __hip_bfloat16 h = __float2bfloat16(f);
    return __builtin_bit_cast(unsigned short, h);
}

// ---------------- token build ----------------
__global__ void build_tokens(const float* __restrict__ text_enc,
                             const float* __restrict__ text_emb,
                             const float* __restrict__ time_tab,
                             const float* __restrict__ lquery,
                             const int* __restrict__ tsteps,
                             float* __restrict__ x) {
    int idx = blockIdx.x * 256 + threadIdx.x;
    if (idx >= NROWS * DIM) return;
    int d = idx % DIM;
    int row = idx / DIM;
    int b = row / NTOK, p = row % NTOK;
    float v;
    if (p < LTXT)            v = text_enc[((size_t)b * LTXT + p) * DIM + d];
    else if (p == LTXT)      v = text_emb[(size_t)b * DIM + d];
    else if (p == LTXT + 1)  v = time_tab[(size_t)tsteps[b] * DIM + d];
    else                     v = lquery[d];
    x[idx] = v;
}

// ---------------- remapped rel-pos bias with mask baked in ----------------
__global__ void build_biasR(const float* __restrict__ table, float* __restrict__ biasR) {
    int idx = blockIdx.x * 256 + threadIdx.x;
    if (idx >= HEADS * NTOK * 96) return;
    int kap = idx % 96;
    int i = (idx / 96) % NTOK;
    int h = idx / (96 * NTOK);
    float v;
    if ((kap < 80 && kap > i) || kap > 80) {
        v = -1e30f;
    } else {
        int j = (kap < 80) ? kap + 1 : 0;
        int rel = j - i;
        int n = rel < 0 ? -rel : 0;
        int bucket;
        if (n < 16) {
            bucket = n;
        } else {
            float val = logf((float)n / 16.0f) / logf(8.0f) * 16.0f;
            int vl = 16 + (int)val;
            bucket = vl < 31 ? vl : 31;
        }
        v = table[bucket * HEADS + h];
    }
    biasR[idx] = v;
}

// ---------------- merged weight transpose+convert: 1 dispatch per layer ----------------
__global__ __launch_bounds__(256) void convT_all(const float* __restrict__ Wq,
                                                 const float* __restrict__ Wkv,
                                                 const float* __restrict__ Wout,
                                                 const float* __restrict__ Wff1,
                                                 const float* __restrict__ Wff2,
                                                 bf16* __restrict__ WqkvT,
                                                 bf16* __restrict__ WoutT,
                                                 bf16* __restrict__ Wff1T,
                                                 bf16* __restrict__ Wff2T) {
    int bid = blockIdx.x;
    const float* W; bf16* WT; int K, N, local;
    if (bid < 576)       { W = Wq;   WT = WqkvT;             K = 768;  N = 768;  local = bid; }
    else if (bid < 672)  { W = Wkv;  WT = WqkvT + 768 * 768; K = 768;  N = 128;  local = bid - 576; }
    else if (bid < 1248) { W = Wout; WT = WoutT;             K = 768;  N = 768;  local = bid - 672; }
    else if (bid < 5856) { W = Wff1; WT = Wff1T;             K = 768;  N = 6144; local = bid - 1248; }
    else                 { W = Wff2; WT = Wff2T;             K = 3072; N = 768;  local = bid - 5856; }
    int nblk = N / 32;
    int n0 = (local % nblk) * 32, k0 = (local / nblk) * 32;

    __shared__ float tt[32][33];
    int tx = threadIdx.x & 31, ty = threadIdx.x >> 5;   // 32 x 8
    #pragma unroll
    for (int i = 0; i < 4; i++)
        tt[ty + 8 * i][tx] = W[(size_t)(k0 + ty + 8 * i) * N + n0 + tx];
    __syncthreads();
    #pragma unroll
    for (int i = 0; i < 4; i++)
        WT[(size_t)(n0 + ty + 8 * i) * K + k0 + tx] = __float2bfloat16(tt[tx][ty + 8 * i]);
}

// ---------------- rmsnorm, wave-per-row, vectorized ----------------
__global__ __launch_bounds__(256) void rmsnorm_w(const float* __restrict__ x,
                                                 const float* __restrict__ gamma,
                                                 bf16* __restrict__ out) {
    int wave = blockIdx.x * 4 + (threadIdx.x >> 6);
    int lane = threadIdx.x & 63;
    float4 g0 = *(const float4*)&gamma[lane * 4];
    float4 g1 = *(const float4*)&gamma[lane * 4 + 256];
    float4 g2 = *(const float4*)&gamma[lane * 4 + 512];
    #pragma unroll 2
    for (int rr = 0; rr < 8; ++rr) {
        int row = wave * 8 + rr;
        const float* xr = x + (size_t)row * DIM + lane * 4;
        float4 v0 = *(const float4*)xr;
        float4 v1 = *(const float4*)(xr + 256);
        float4 v2 = *(const float4*)(xr + 512);
        float ss = v0.x*v0.x + v0.y*v0.y + v0.z*v0.z + v0.w*v0.w
                 + v1.x*v1.x + v1.y*v1.y + v1.z*v1.z + v1.w*v1.w
                 + v2.x*v2.x + v2.y*v2.y + v2.z*v2.z + v2.w*v2.w;
        #pragma unroll
        for (int o = 32; o > 0; o >>= 1) ss += __shfl_xor(ss, o);
        float inv = 27.712812921102035f / sqrtf(ss + 1e-5f);
        bf16* orow = out + (size_t)row * DIM + lane * 4;
        ushort4 w0 = { f2bf(v0.x*inv*g0.x), f2bf(v0.y*inv*g0.y), f2bf(v0.z*inv*g0.z), f2bf(v0.w*inv*g0.w) };
        ushort4 w1 = { f2bf(v1.x*inv*g1.x), f2bf(v1.y*inv*g1.y), f2bf(v1.z*inv*g1.z), f2bf(v1.w*inv*g1.w) };
        ushort4 w2 = { f2bf(v2.x*inv*g2.x), f2bf(v2.y*inv*g2.y), f2bf(v2.z*inv*g2.z), f2bf(v2.w*inv*g2.w) };
        *(ushort4*)(orow)       = w0;
        *(ushort4*)(orow + 256) = w1;
        *(ushort4*)(orow + 512) = w2;
    }
}

// rmsnorm for last layer: only rows i*80+79 (256 rows), compact output
__global__ __launch_bounds__(256) void rmsnorm_last(const float* __restrict__ x,
                                                    const float* __restrict__ gamma,
                                                    bf16* __restrict__ out) {
    int wave = blockIdx.x * 4 + (threadIdx.x >> 6);
    int lane = threadIdx.x & 63;
    float4 g0 = *(const float4*)&gamma[lane * 4];
    float4 g1 = *(const float4*)&gamma[lane * 4 + 256];
    float4 g2 = *(const float4*)&gamma[lane * 4 + 512];
    #pragma unroll 2
    for (int rr = 0; rr < 8; ++rr) {
        int row = wave * 8 + rr;                       // 0..255 (batch index)
        const float* xr = x + ((size_t)row * NTOK + 79) * DIM + lane * 4;
        float4 v0 = *(const float4*)xr;
        float4 v1 = *(const float4*)(xr + 256);
        float4 v2 = *(const float4*)(xr + 512);
        float ss = v0.x*v0.x + v0.y*v0.y + v0.z*v0.z + v0.w*v0.w
                 + v1.x*v1.x + v1.y*v1.y + v1.z*v1.z + v1.w*v1.w
                 + v2.x*v2.x + v2.y*v2.y + v2.z*v2.z + v2.w*v2.w;
        #pragma unroll
        for (int o = 32; o > 0; o >>= 1) ss += __shfl_xor(ss, o);
        float inv = 27.712812921102035f / sqrtf(ss + 1e-5f);
        bf16* orow = out + (size_t)row * DIM + lane * 4;
        ushort4 w0 = { f2bf(v0.x*inv*g0.x), f2bf(v0.y*inv*g0.y), f2bf(v0.z*inv*g0.z), f2bf(v0.w*inv*g0.w) };
        ushort4 w1 = { f2bf(v1.x*inv*g1.x), f2bf(v1.y*inv*g1.y), f2bf(v1.z*inv*g1.z), f2bf(v1.w*inv*g1.w) };
        ushort4 w2 = { f2bf(v2.x*inv*g2.x), f2bf(v2.y*inv*g2.y), f2bf(v2.z*inv*g2.z), f2bf(v2.w*inv*g2.w) };
        *(ushort4*)(orow)       = w0;
        *(ushort4*)(orow + 256) = w1;
        *(ushort4*)(orow + 512) = w2;
    }
}

// =========================================================================
// bf16 MFMA GEMM, 128x128 tile, 16x16x32 MFMA, phase-split schedule:
// each K-tile = 2 phases x {WAITV(4)+barrier (phase0 only) -> stage one
// half-item (4 loads) -> ds_read -> setprio 16 MFMA -> barrier}.
// Stage stream runs 3 phases ahead of consumption -> loads fly ~2 phases;
// gate is vmcnt(4) (only the newest item in flight), vmcnt(0) only at the
// last tile. Buffer overwrites are issued strictly after the barrier that
// follows the last reads of that buffer (af register-carried).
// LDS dest linear; conflict-free via pre-swizzled global source chunk
// (c ^ row&7) + same XOR on fragment read (2-way aliasing = free).
// =========================================================================

#define GSTAGE_N(nld, lds, base, b0, ld, kk0)                                  \
    _Pragma("unroll")                                                          \
    for (int r_ = 0; r_ < (nld); ++r_) {                                       \
        int idx_ = r_ * 256 + t;                                               \
        int row_ = idx_ >> 3, c_ = idx_ & 7;                                   \
        int cs_ = c_ ^ (row_ & 7);                                             \
        __builtin_amdgcn_global_load_lds(                                      \
            (const __attribute__((address_space(1))) unsigned int*)            \
                &base[(size_t)(b0 + row_) * (ld) + (kk0) + cs_ * 8],           \
            (__attribute__((address_space(3))) unsigned int*)&lds[idx_ * 8],   \
            16, 0, 0);                                                         \
    }

#define FRAG_READ(dst, lds, base_row, kk)                                      \
    _Pragma("unroll")                                                          \
    for (int q_ = 0; q_ < 4; ++q_) {                                           \
        int row_ = (base_row) + q_ * 16 + fr;                                  \
        int ch_ = ((((kk) << 2) + kb) ^ (row_ & 7));                           \
        dst[q_] = *(const short8*)&lds[row_ * 64 + ch_ * 8];                   \
    }

#define FRAG_READ2(dst, lds, base_row, kk)                                     \
    _Pragma("unroll")                                                          \
    for (int q_ = 0; q_ < 2; ++q_) {                                           \
        int row_ = (base_row) + q_ * 16 + fr;                                  \
        int ch_ = ((((kk) << 2) + kb) ^ (row_ & 7));                           \
        dst[q_] = *(const short8*)&lds[row_ * 64 + ch_ * 8];                   \
    }

// lda = A row stride, ldc = C row stride (elements). C(f32) += acc.
template<int EPI>
__global__ __launch_bounds__(256, 2) void gemm_bt(const bf16* __restrict__ A,
                                                  const bf16* __restrict__ BT,
                                                  float* __restrict__ C,
                                                  int N, int K, int lda, int ldc) {
    __shared__ __align__(16) short As[2 * 128 * 64];
    __shared__ __align__(16) short Bs[2 * 128 * 64];
    const int t = threadIdx.x;
    const int lane = t & 63;
    const int wid = t >> 6;
    const int wr = wid >> 1, wc = wid & 1;
    const int fr = lane & 15;
    const int kb = lane >> 4;
    const int row0 = blockIdx.y * 128, col0 = blockIdx.x * 128;

    f32x4 acc[4][4] = {};
    const int NKT = K >> 6;

    // prologue: A(0)->As0, B(0)->Bs0, A(1)->As1 (3-phase stage lead)
    GSTAGE_N(4, As, A, row0, lda, 0)
    GSTAGE_N(4, Bs, BT, col0, K, 0)
    {
        short* As1 = As + 128 * 64;
        GSTAGE_N(4, As1, A, row0, lda, 64)
    }

    for (int kt = 0; kt < NKT; ++kt) {
        const short* curA = As + (kt & 1) * (128 * 64);
        const short* curB = Bs + (kt & 1) * (128 * 64);
        // gate: everything except the newest in-flight item (A(kt+1)) retired
        if (kt == NKT - 1) { WAITV(0); } else { WAITV(4); }
        BARRIER();
        short8 af0[4], af1[4];
        {   // ---------- phase 0: MFMA on acc[:, 0..1] ----------
            if (kt + 1 < NKT) {
                short* nb = Bs + ((kt + 1) & 1) * (128 * 64);
                int k0n = (kt + 1) << 6;
                GSTAGE_N(4, nb, BT, col0, K, k0n)     // B(kt+1), lands >= gate of kt+1
            }
            short8 bv0[2], bv1[2];
            FRAG_READ(af0, curA, wr * 64, 0)
            FRAG_READ(af1, curA, wr * 64, 1)
            FRAG_READ2(bv0, curB, wc * 64, 0)
            FRAG_READ2(bv1, curB, wc * 64, 1)
            __builtin_amdgcn_s_setprio(1);
            #pragma unroll
            for (int i = 0; i < 4; ++i)
                #pragma unroll
                for (int j = 0; j < 2; ++j) {
                    acc[i][j] = __builtin_amdgcn_mfma_f32_16x16x32_bf16(af0[i], bv0[j], acc[i][j], 0, 0, 0);
                    acc[i][j] = __builtin_amdgcn_mfma_f32_16x16x32_bf16(af1[i], bv1[j], acc[i][j], 0, 0, 0);
                }
            __builtin_amdgcn_s_setprio(0);
        }
        BARRIER();
        {   // ---------- phase 1: MFMA on acc[:, 2..3] ----------
            if (kt + 2 < NKT) {
                short* na = As + (kt & 1) * (128 * 64);   // (kt+2)&1 == kt&1; af done reading
                int k0n = (kt + 2) << 6;
                GSTAGE_N(4, na, A, row0, lda, k0n)        // A(kt+2)
            }
            short8 bw0[2], bw1[2];
            FRAG_READ2(bw0, curB, wc * 64 + 32, 0)
            FRAG_READ2(bw1, curB, wc * 64 + 32, 1)
            __builtin_amdgcn_s_setprio(1);
            #pragma unroll
            for (int i = 0; i < 4; ++i)
                #pragma unroll
                for (int j = 0; j < 2; ++j) {
                    acc[i][j + 2] = __builtin_amdgcn_mfma_f32_16x16x32_bf16(af0[i], bw0[j], acc[i][j + 2], 0, 0, 0);
                    acc[i][j + 2] = __builtin_amdgcn_mfma_f32_16x16x32_bf16(af1[i], bw1[j], acc[i][j + 2], 0, 0, 0);
                }
            __builtin_amdgcn_s_setprio(0);
        }
        BARRIER();
    }

    #pragma unroll
    for (int i = 0; i < 4; ++i) {
        #pragma unroll
        for (int j = 0; j < 4; ++j) {
            int row = row0 + wr * 64 + i * 16 + kb * 4;
            int col = col0 + wc * 64 + j * 16 + fr;
            #pragma unroll
            for (int r = 0; r < 4; ++r) {
                size_t o = (size_t)(row + r) * ldc + col;
                C[o] += acc[i][j][r];
            }
        }
    }
}

// =========================================================================
// fused QKV: BT = WqkvT [896][768]. Same phase-split body as gemm_bt.
// =========================================================================
__global__ __launch_bounds__(256, 2) void gemm_qkv(const bf16* __restrict__ A,
                                                   const bf16* __restrict__ BT,
                                                   bf16* __restrict__ qb,
                                                   bf16* __restrict__ kout,
                                                   bf16* __restrict__ vT) {
    __shared__ __align__(16) short As[2 * 128 * 64];
    __shared__ __align__(16) short Bs[2 * 128 * 64];
    const int t = threadIdx.x;
    const int lane = t & 63;
    const int wid = t >> 6;
    const int wr = wid >> 1, wc = wid & 1;
    const int fr = lane & 15;
    const int kb = lane >> 4;
    const int row0 = blockIdx.y * 128, col0 = blockIdx.x * 128;
    const int K = DIM;

    f32x4 acc[4][4] = {};
    const int NKT = DIM >> 6;

    GSTAGE_N(4, As, A, row0, K, 0)
    GSTAGE_N(4, Bs, BT, col0, K, 0)
    {
        short* As1 = As + 128 * 64;
        GSTAGE_N(4, As1, A, row0, K, 64)
    }

    for (int kt = 0; kt < NKT; ++kt) {
        const short* curA = As + (kt & 1) * (128 * 64);
        const short* curB = Bs + (kt & 1) * (128 * 64);
        if (kt == NKT - 1) { WAITV(0); } else { WAITV(4); }
        BARRIER();
        short8 af0[4], af1[4];
        {
            if (kt + 1 < NKT) {
                short* nb = Bs + ((kt + 1) & 1) * (128 * 64);
                int k0n = (kt + 1) << 6;
                GSTAGE_N(4, nb, BT, col0, K, k0n)
            }
            short8 bv0[2], bv1[2];
            FRAG_READ(af0, curA, wr * 64, 0)
            FRAG_READ(af1, curA, wr * 64, 1)
            FRAG_READ2(bv0, curB, wc * 64, 0)
            FRAG_READ2(bv1, curB, wc * 64, 1)
            __builtin_amdgcn_s_setprio(1);
            #pragma unroll
            for (int i = 0; i < 4; ++i)
                #pragma unroll
                for (int j = 0; j < 2; ++j) {
                    acc[i][j] = __builtin_amdgcn_mfma_f32_16x16x32_bf16(af0[i], bv0[j], acc[i][j], 0, 0, 0);
                    acc[i][j] = __builtin_amdgcn_mfma_f32_16x16x32_bf16(af1[i], bv1[j], acc[i][j], 0, 0, 0);
                }
            __builtin_amdgcn_s_setprio(0);
        }
        BARRIER();
        {
            if (kt + 2 < NKT) {
                short* na = As + (kt & 1) * (128 * 64);
                int k0n = (kt + 2) << 6;
                GSTAGE_N(4, na, A, row0, K, k0n)
            }
            short8 bw0[2], bw1[2];
            FRAG_READ2(bw0, curB, wc * 64 + 32, 0)
            FRAG_READ2(bw1, curB, wc * 64 + 32, 1)
            __builtin_amdgcn_s_setprio(1);
            #pragma unroll
            for (int i = 0; i < 4; ++i)
                #pragma unroll
                for (int j = 0; j < 2; ++j) {
                    acc[i][j + 2] = __builtin_amdgcn_mfma_f32_16x16x32_bf16(af0[i], bw0[j], acc[i][j + 2], 0, 0, 0);
                    acc[i][j + 2] = __builtin_amdgcn_mfma_f32_16x16x32_bf16(af1[i], bw1[j], acc[i][j + 2], 0, 0, 0);
                }
            __builtin_amdgcn_s_setprio(0);
        }
        BARRIER();
    }

    if (col0 < 768) {
        #pragma unroll
        for (int i = 0; i < 4; ++i) {
            #pragma unroll
            for (int j = 0; j < 4; ++j) {
                int row = row0 + wr * 64 + i * 16 + kb * 4;
                int col = col0 + wc * 64 + j * 16 + fr;
                #pragma unroll
                for (int r = 0; r < 4; ++r)
                    qb[(size_t)(row + r) * INNER + col] = __float2bfloat16(acc[i][j][r]);
            }
        }
    } else {
        #pragma unroll
        for (int i = 0; i < 4; ++i) {
            #pragma unroll
            for (int j = 0; j < 4; ++j) {
                int row = row0 + wr * 64 + i * 16 + kb * 4;
                int col = wc * 64 + j * 16 + fr;   // 0..127 local
                #pragma unroll
                for (int r = 0; r < 4; ++r) {
                    int rg = row + r;
                    float v = acc[i][j][r];
                    if (wc == 0) {
                        kout[(size_t)rg * 64 + col] = __float2bfloat16(v);
                    } else {
                        int bb = rg / NTOK, ii = rg - bb * NTOK;
                        vT[((size_t)bb * 64 + (col - 64)) * NTOK + ii] = __float2bfloat16(v);
                    }
                }
            }
        }
    }
}

// =========================================================================
// fused FF1: act = (A@W1a) * silu(A@W1g). 128x64 tile, phase-split:
// phase0 = acc1 (a-cols), phase1 = acc2 (gate-cols). Same lead/gating.
// =========================================================================
__global__ __launch_bounds__(256, 2) void gemm_ff1(const bf16* __restrict__ A,
                                                   const bf16* __restrict__ W1T,
                                                   bf16* __restrict__ act) {
    __shared__ __align__(16) short As[2 * 128 * 64];
    __shared__ __align__(16) short Bs1[2 * 64 * 64];
    __shared__ __align__(16) short Bs2[2 * 64 * 64];
    const int t = threadIdx.x;
    const int lane = t & 63;
    const int wid = t >> 6;
    const int wr = wid >> 1, wc = wid & 1;
    const int fr = lane & 15;
    const int kb = lane >> 4;
    const int row0 = blockIdx.y * 128, col0 = blockIdx.x * 64;
    const int K = DIM;
    const bf16* B1 = W1T;
    const bf16* B2 = W1T + (size_t)FFH * DIM;

    f32x4 acc1[4][2] = {}, acc2[4][2] = {};
    const int NKT = DIM >> 6;

    GSTAGE_N(4, As, A, row0, K, 0)
    GSTAGE_N(2, Bs1, B1, col0, K, 0)
    GSTAGE_N(2, Bs2, B2, col0, K, 0)
    {
        short* As1 = As + 128 * 64;
        GSTAGE_N(4, As1, A, row0, K, 64)
    }

    for (int kt = 0; kt < NKT; ++kt) {
        const short* curA  = As  + (kt & 1) * (128 * 64);
        const short* curB1 = Bs1 + (kt & 1) * (64 * 64);
        const short* curB2 = Bs2 + (kt & 1) * (64 * 64);
        if (kt == NKT - 1) { WAITV(0); } else { WAITV(4); }
        BARRIER();
        short8 af0[4], af1[4];
        {   // phase 0: acc1
            if (kt + 1 < NKT) {
                short* nb1 = Bs1 + ((kt + 1) & 1) * (64 * 64);
                short* nb2 = Bs2 + ((kt + 1) & 1) * (64 * 64);
                int k0n = (kt + 1) << 6;
                GSTAGE_N(2, nb1, B1, col0, K, k0n)
                GSTAGE_N(2, nb2, B2, col0, K, k0n)
            }
            short8 b10[2], b11[2];
            FRAG_READ(af0, curA, wr * 64, 0)
            FRAG_READ(af1, curA, wr * 64, 1)
            FRAG_READ2(b10, curB1, wc * 32, 0)
            FRAG_READ2(b11, curB1, wc * 32, 1)
            __builtin_amdgcn_s_setprio(1);
            #pragma unroll
            for (int i = 0; i < 4; ++i)
                #pragma unroll
                for (int j = 0; j < 2; ++j) {
                    acc1[i][j] = __builtin_amdgcn_mfma_f32_16x16x32_bf16(af0[i], b10[j], acc1[i][j], 0, 0, 0);
                    acc1[i][j] = __builtin_amdgcn_mfma_f32_16x16x32_bf16(af1[i], b11[j], acc1[i][j], 0, 0, 0);
                }
            __builtin_amdgcn_s_setprio(0);
        }
        BARRIER();
        {   // phase 1: acc2
            if (kt + 2 < NKT) {
                short* na = As + (kt & 1) * (128 * 64);
                int k0n = (kt + 2) << 6;
                GSTAGE_N(4, na, A, row0, K, k0n)
            }
            short8 b20[2], b21[2];
            FRAG_READ2(b20, curB2, wc * 32, 0)
            FRAG_READ2(b21, curB2, wc * 32, 1)
            __builtin_amdgcn_s_setprio(1);
            #pragma unroll
            for (int i = 0; i < 4; ++i)
                #pragma unroll
                for (int j = 0; j < 2; ++j) {
                    acc2[i][j] = __builtin_amdgcn_mfma_f32_16x16x32_bf16(af0[i], b20[j], acc2[i][j], 0, 0, 0);
                    acc2[i][j] = __builtin_amdgcn_mfma_f32_16x16x32_bf16(af1[i], b21[j], acc2[i][j], 0, 0, 0);
                }
            __builtin_amdgcn_s_setprio(0);
        }
        BARRIER();
    }

    #pragma unroll
    for (int i = 0; i < 4; ++i) {
        #pragma unroll
        for (int j = 0; j < 2; ++j) {
            int row = row0 + wr * 64 + i * 16 + kb * 4;
            int col = col0 + wc * 32 + j * 16 + fr;
            #pragma unroll
            for (int r = 0; r < 4; ++r) {
                float a = acc1[i][j][r];
                float gt = acc2[i][j][r];
                float s = a * gt / (1.0f + __expf(-gt));
                act[(size_t)(row + r) * FFH + col] = __float2bfloat16(s);
            }
        }
    }
}

// =========================================================================
// MFMA attention: one block per (b,h), 4 waves. (unchanged)
// =========================================================================
__global__ __launch_bounds__(256) void attn_mfma(const bf16* __restrict__ qb,
                                                 const bf16* __restrict__ kbuf,
                                                 const bf16* __restrict__ vT,
                                                 const float* __restrict__ nullkv,  // [2][64] this layer
                                                 const float* __restrict__ biasR,
                                                 bf16* __restrict__ attnb) {
    const int b = blockIdx.x / HEADS;
    const int h = blockIdx.x % HEADS;
    __shared__ __align__(16) short Ks[96 * 64];
    __shared__ __align__(16) short Vt[64 * 128];
    __shared__ __align__(16) float Sls[80 * SROW];
    char* Sb = (char*)Sls;
    const int t = threadIdx.x;
    const int lane = t & 63;
    const int wid = t >> 6;
    const int g = lane >> 4;
    const int fr = lane & 15;

    for (int c = t; c < 768; c += 256) {
        int row = c >> 3, ch = c & 7;
        short8 v;
        if (row < NTOK) {
            v = *(const short8*)&kbuf[((size_t)(b * NTOK + row)) * 64 + ch * 8];
        } else if (row == NTOK) {
            #pragma unroll
            for (int e = 0; e < 8; ++e) v[e] = (short)f2bf(nullkv[ch * 8 + e]);
        } else {
            v = short8{0,0,0,0,0,0,0,0};
        }
        *(short8*)((char*)Ks + row * 128 + ((ch ^ (row & 7)) << 4)) = v;
    }
    for (int c = t; c < 1024; c += 256) {
        int d = c >> 4, ch = c & 15;
        if (ch >= 12) continue;
        short8 v;
        if (ch < 10) {
            v = *(const short8*)&vT[((size_t)b * 64 + d) * NTOK + ch * 8];
        } else if (ch == 10) {
            v = short8{0,0,0,0,0,0,0,0};
            v[0] = (short)f2bf(nullkv[64 + d]);
        } else {
            v = short8{0,0,0,0,0,0,0,0};
        }
        *(short8*)((char*)Vt + d * 256 + ((ch ^ (d & 7)) << 4)) = v;
    }
    __syncthreads();

    const bf16* qbase = qb + ((size_t)(b * NTOK)) * INNER + h * DH;
    for (int s = 0; s < 8; ++s) {
        int tt = wid + 4 * s;
        if (tt >= 30) break;
        int m = tt / 6, n = tt - 6 * m;
        f32x4 acc = {};
        #pragma unroll
        for (int kk = 0; kk < 2; ++kk) {
            short8 a = *(const short8*)&qbase[(size_t)(m * 16 + fr) * INNER + kk * 32 + g * 8];
            int krow = n * 16 + fr;
            short8 kf = *(const short8*)((const char*)Ks + krow * 128 + ((((kk << 2) + g) ^ (krow & 7)) << 4));
            acc = __builtin_amdgcn_mfma_f32_16x16x32_bf16(a, kf, acc, 0, 0, 0);
        }
        int i0 = m * 16 + g * 4;
        int kap = n * 16 + fr;
        const float* bR = biasR + ((size_t)h * NTOK + i0) * 96 + kap;
        #pragma unroll
        for (int r = 0; r < 4; ++r)
            Sls[(i0 + r) * SROW + kap] = acc[r] * 0.125f + bR[r * 96];
    }
    __syncthreads();

    for (int rr = 0; rr < 20; ++rr) {
        int row = wid + 4 * rr;
        const float* Srow = Sls + row * SROW;
        float s0 = Srow[lane];
        float s1v = Srow[64 + (lane & 31)];
        float mx = fmaxf(s0, s1v);
        #pragma unroll
        for (int o = 32; o > 0; o >>= 1) mx = fmaxf(mx, __shfl_xor(mx, o));
        float e0 = __expf(s0 - mx);
        float e1 = (lane < 32) ? __expf(s1v - mx) : 0.0f;
        float sum = e0 + e1;
        #pragma unroll
        for (int o = 32; o > 0; o >>= 1) sum += __shfl_xor(sum, o);
        float inv = 1.0f / sum;
        *(unsigned short*)(Sb + row * (SROW * 4) + lane * 2) = f2bf(e0 * inv);
        if (lane < 32)
            *(unsigned short*)(Sb + row * (SROW * 4) + 128 + lane * 2) = f2bf(e1 * inv);
    }
    __syncthreads();

    for (int s = 0; s < 5; ++s) {
        int tt = wid + 4 * s;
        int m = tt >> 2, n = tt & 3;
        f32x4 acc = {};
        #pragma unroll
        for (int kc = 0; kc < 3; ++kc) {
            short8 p = *(const short8*)(Sb + (m * 16 + fr) * (SROW * 4) + kc * 64 + g * 16);
            int drow = n * 16 + fr;
            short8 vv = *(const short8*)((const char*)Vt + drow * 256 + ((((kc << 2) + g) ^ (drow & 7)) << 4));
            acc = __builtin_amdgcn_mfma_f32_16x16x32_bf16(p, vv, acc, 0, 0, 0);
        }
        int i0 = m * 16 + g * 4;
        int d = n * 16 + fr;
        #pragma unroll
        for (int r = 0; r < 4; ++r)
            attnb[((size_t)(b * NTOK) + i0 + r) * INNER + h * DH + d] = __float2bfloat16(acc[r]);
    }
}

// ---------------- output extraction ----------------
__global__ void extract(const float* __restrict__ x, float* __restrict__ out) {
    int idx = blockIdx.x * 256 + threadIdx.x;
    if (idx >= NB * DIM) return;
    int b = idx / DIM, d = idx % DIM;
    out[idx] = x[((size_t)(b * NTOK + NTOK - 1)) * DIM + d];
}

extern "C" void kernel_launch(void* const* d_in, const int* in_sizes, int n_in,
                              void* d_out, int out_size, void* d_ws, size_t ws_size,
                              hipStream_t stream) {
    (void)in_sizes; (void)n_in; (void)out_size; (void)ws_size;
    const float* text_enc = (const float*)d_in[1];
    const float* text_emb = (const float*)d_in[2];
    const float* time_tab = (const float*)d_in[3];
    const float* lquery   = (const float*)d_in[4];
    const float* rel_tab  = (const float*)d_in[5];
    const float* attn_g   = (const float*)d_in[6];
    const float* Wq       = (const float*)d_in[7];
    const float* Wkv      = (const float*)d_in[8];
    const float* Wout     = (const float*)d_in[9];
    const float* null_kv  = (const float*)d_in[10];
    const float* ff_g     = (const float*)d_in[11];
    const float* Wff1     = (const float*)d_in[12];
    const float* Wff2     = (const float*)d_in[13];
    const int*   tsteps   = (const int*)d_in[14];

    // ---- workspace layout (bytes, all 16-aligned) ----
    char* ws = (char*)d_ws;
    float* x     = (float*)(ws);                        // 62,914,560
    bf16*  xn    = (bf16*)(ws + 62914560);              // 31,457,280 (attn out aliases)
    bf16*  attnb = xn;
    char*  U     = ws + 94371840;                       // union region: 125,829,120
    bf16*  qb    = (bf16*)U;                            //  31,457,280
    bf16*  kbuf  = (bf16*)(U + 31457280);               //   2,621,440
    bf16*  vT    = (bf16*)(U + 34078720);               //   2,621,440
    bf16*  act   = (bf16*)U;                            // 125,829,120 (FF phase)
    float* biasR = (float*)(ws + 220200960);            //     368,640
    bf16*  WqkvT = (bf16*)(ws + 220569600);             //   1,376,256 ([896][768])
    bf16*  WoutT = (bf16*)(ws + 221945856);             //   1,179,648
    bf16*  Wff1T = (bf16*)(ws + 223125504);             //   9,437,184
    bf16*  Wff2T = (bf16*)(ws + 232562688);             //   4,718,592  -> end 237,281,280

    build_tokens<<<(NROWS * DIM + 255) / 256, 256, 0, stream>>>(text_enc, text_emb, time_tab, lquery, tsteps, x);
    build_biasR<<<(HEADS * NTOK * 96 + 255) / 256, 256, 0, stream>>>(rel_tab, biasR);

    for (int l = 0; l < DEPTH; l++) {
        convT_all<<<8160, 256, 0, stream>>>(Wq   + (size_t)l * DIM * INNER,
                                            Wkv  + (size_t)l * DIM * 2 * DH,
                                            Wout + (size_t)l * INNER * DIM,
                                            Wff1 + (size_t)l * DIM * FF2C,
                                            Wff2 + (size_t)l * FFH * DIM,
                                            WqkvT, WoutT, Wff1T, Wff2T);

        // ---- attention block ----
        rmsnorm_w<<<NROWS / 32, 256, 0, stream>>>(x, attn_g + (size_t)l * DIM, xn);
        gemm_qkv<<<dim3(7, NROWS / 128), 256, 0, stream>>>(xn, WqkvT, qb, kbuf, vT);
        attn_mfma<<<NB * HEADS, 256, 0, stream>>>(qb, kbuf, vT, null_kv + (size_t)l * 2 * DH, biasR, attnb);

        if (l < DEPTH - 1) {
            gemm_bt<1><<<dim3(DIM / 128, NROWS / 128), 256, 0, stream>>>(attnb, WoutT, x, DIM, INNER, INNER, DIM);
            // ---- feedforward block ----
            rmsnorm_w<<<NROWS / 32, 256, 0, stream>>>(x, ff_g + (size_t)l * DIM, xn);
            gemm_ff1<<<dim3(FFH / 64, NROWS / 128), 256, 0, stream>>>(xn, Wff1T, act);
            gemm_bt<1><<<dim3(DIM / 128, NROWS / 128), 256, 0, stream>>>(act, Wff2T, x, DIM, FFH, FFH, DIM);
        } else {
            // ---- last layer: only token 79 per batch feeds the output ----
            gemm_bt<1><<<dim3(DIM / 128, 2), 256, 0, stream>>>(
                attnb + (size_t)79 * INNER, WoutT, x + (size_t)79 * DIM,
                DIM, INNER, NTOK * INNER, NTOK * DIM);
            rmsnorm_last<<<8, 256, 0, stream>>>(x, ff_g + (size_t)l * DIM, xn);
            gemm_ff1<<<dim3(FFH / 64, 2), 256, 0, stream>>>(xn, Wff1T, act);
            gemm_bt<1><<<dim3(DIM / 128, 2), 256, 0, stream>>>(
                act, Wff2T, x + (size_t)79 * DIM,
                DIM, FFH, FFH, NTOK * DIM);
        }
    }

    extract<<<(NB * DIM + 255) / 256, 256, 0, stream>>>(x, (float*)d_out);
}